// Round 1
// baseline (4377.302 us; speedup 1.0000x reference)
//
#include <hip/hip_runtime.h>
#include <hip/hip_bf16.h>
#include <math.h>

// Shapes (fixed by the reference)
#define S_   64
#define B_   1024
#define D_   512
#define H_   8
#define NL_  4
#define DH_  64
#define DFF_ 2048
#define NTOK (S_*B_)   // 65536 tokens

typedef __bf16 bf16;
typedef __bf16 bf16x8 __attribute__((ext_vector_type(8)));
typedef float  f32x4  __attribute__((ext_vector_type(4)));

#define AS1(p) ((__attribute__((address_space(1))) void*)(void*)(p))
#define AS3(p) ((__attribute__((address_space(3))) void*)(p))

// ---------------------------------------------------------------------------
// fp32 -> bf16 elementwise convert (weights; n multiple of 4)
__global__ __launch_bounds__(256) void cvt_k(const float* __restrict__ s,
                                             bf16* __restrict__ d, int n) {
    int i = (blockIdx.x * 256 + threadIdx.x) * 4;
    if (i < n) {
        float4 v = *(const float4*)(s + i);
        bf16 o4[4] = {(bf16)v.x, (bf16)v.y, (bf16)v.z, (bf16)v.w};
        *(ushort4*)(d + i) = *(const ushort4*)o4;  // 8B store
    }
}

// ---------------------------------------------------------------------------
// X = x + positional encoding (computed on the fly). One thread per (sin,cos) pair.
__global__ __launch_bounds__(256) void pe_add_k(const float* __restrict__ x,
                                                float* __restrict__ X) {
    int id = blockIdx.x * 256 + threadIdx.x;   // pair id, 0..N*256-1
    int n = id >> 8;                            // token row = s*B+b
    int j = id & 255;                           // pair index, d = 2j
    int s = n >> 10;                            // n / B_
    // div_j = exp(-(2j) * ln(10000)/512); 2*ln(10000)/512 = 0.03597789207803197
    float div = expf((float)j * -0.03597789207803197f);
    float ang = (float)s * div;
    const float inv = 0.04419417382415922f;     // 1/sqrt(512)
    float2 v = *(const float2*)(x + (long)n * 512 + 2 * j);
    v.x += sinf(ang) * inv;
    v.y += cosf(ang) * inv;
    *(float2*)(X + (long)n * 512 + 2 * j) = v;
}

// ---------------------------------------------------------------------------
// LayerNorm: one wave per row (D=512, 8 floats/lane), fp32 math, bf16 out.
__global__ __launch_bounds__(256) void ln_k(const float* __restrict__ X,
                                            const float* __restrict__ g,
                                            const float* __restrict__ be,
                                            bf16* __restrict__ out) {
    long row = (long)blockIdx.x * 4 + (threadIdx.x >> 6);
    int lane = threadIdx.x & 63;
    const float* xr = X + row * 512 + lane * 8;
    float4 v0 = *(const float4*)xr;
    float4 v1 = *(const float4*)(xr + 4);
    float vv[8] = {v0.x, v0.y, v0.z, v0.w, v1.x, v1.y, v1.z, v1.w};
    float s = 0.f, sq = 0.f;
    #pragma unroll
    for (int j = 0; j < 8; j++) { s += vv[j]; sq += vv[j] * vv[j]; }
    #pragma unroll
    for (int off = 1; off < 64; off <<= 1) {
        s  += __shfl_xor(s, off);
        sq += __shfl_xor(sq, off);
    }
    float mean = s * (1.f / 512.f);
    float var  = sq * (1.f / 512.f) - mean * mean;
    float rs = rsqrtf(var + 1e-5f);
    int d = lane * 8;
    bf16 o8[8];
    #pragma unroll
    for (int j = 0; j < 8; j++)
        o8[j] = (bf16)((vv[j] - mean) * rs * g[d + j] + be[d + j]);
    *(uint4*)(out + row * 512 + d) = *(const uint4*)o8;  // 16B store
}

// ---------------------------------------------------------------------------
// GEMM: C[n,m] = A[n,k] * Bw[m,k] + bias[m]  (B^T layout, both K-contiguous).
// 128x128 tile, BK=32, 4 waves, each wave 4x4 tiles of mfma_f32_16x16x32_bf16.
// EPI 0: write bf16. EPI 1: QuickGELU then bf16. EPI 2: fp32 residual +=.
template<int EPI>
__global__ __launch_bounds__(256)
void gemm_bt(const bf16* __restrict__ A, const bf16* __restrict__ Bw,
             const float* __restrict__ bias, float* __restrict__ Xres,
             bf16* __restrict__ Obf, int Mdim, int K) {
    __shared__ bf16 As[128 * 32];
    __shared__ bf16 Bs[128 * 32];
    const int tid  = threadIdx.x;
    const int lane = tid & 63;
    const int wave = tid >> 6;
    const long rowBlk = (long)blockIdx.y * 128;
    const long colBlk = (long)blockIdx.x * 128;

    // staging: chunk c (16B) covers tile row c>>2, k-offset (c&3)*8.
    // c = wave*64 + lane  => LDS dest is wave-uniform base + lane*16 (required).
    const int c0 = tid;
    const bf16* ag0 = A  + (rowBlk + (c0 >> 2)) * K + (c0 & 3) * 8;
    const bf16* ag1 = ag0 + 64 * (long)K;
    const bf16* bg0 = Bw + (colBlk + (c0 >> 2)) * K + (c0 & 3) * 8;
    const bf16* bg1 = bg0 + 64 * (long)K;
    bf16* al0 = As + c0 * 8;
    bf16* al1 = As + (c0 + 256) * 8;
    bf16* bl0 = Bs + c0 * 8;
    bf16* bl1 = Bs + (c0 + 256) * 8;

    const int wm = (wave >> 1) * 64, wn = (wave & 1) * 64;
    const int lr = lane & 15, lq = lane >> 4;

    f32x4 acc[4][4] = {};

    for (int k0 = 0; k0 < K; k0 += 32) {
        __builtin_amdgcn_global_load_lds(AS1(ag0 + k0), AS3(al0), 16, 0, 0);
        __builtin_amdgcn_global_load_lds(AS1(ag1 + k0), AS3(al1), 16, 0, 0);
        __builtin_amdgcn_global_load_lds(AS1(bg0 + k0), AS3(bl0), 16, 0, 0);
        __builtin_amdgcn_global_load_lds(AS1(bg1 + k0), AS3(bl1), 16, 0, 0);
        __syncthreads();   // drains vmcnt, barrier
        bf16x8 af[4], bfr[4];
        #pragma unroll
        for (int mi = 0; mi < 4; mi++)
            af[mi] = *(const bf16x8*)(As + (wm + mi * 16 + lr) * 32 + lq * 8);
        #pragma unroll
        for (int ni = 0; ni < 4; ni++)
            bfr[ni] = *(const bf16x8*)(Bs + (wn + ni * 16 + lr) * 32 + lq * 8);
        #pragma unroll
        for (int mi = 0; mi < 4; mi++)
            #pragma unroll
            for (int ni = 0; ni < 4; ni++)
                acc[mi][ni] = __builtin_amdgcn_mfma_f32_16x16x32_bf16(
                    af[mi], bfr[ni], acc[mi][ni], 0, 0, 0);
        __syncthreads();   // frag reads done before next stage overwrites LDS
    }

    // epilogue: C/D layout col=lane&15, row=(lane>>4)*4+reg  [verified m89/m91]
    #pragma unroll
    for (int mi = 0; mi < 4; mi++) {
        #pragma unroll
        for (int ni = 0; ni < 4; ni++) {
            #pragma unroll
            for (int r = 0; r < 4; r++) {
                long row = rowBlk + wm + mi * 16 + lq * 4 + r;
                long col = colBlk + wn + ni * 16 + lr;
                float v = acc[mi][ni][r] + bias[col];
                if (EPI == 0) {
                    Obf[row * Mdim + col] = (bf16)v;
                } else if (EPI == 1) {
                    float gv = v / (1.f + __expf(-1.702f * v));  // QuickGELU
                    Obf[row * Mdim + col] = (bf16)gv;
                } else {
                    Xres[row * Mdim + col] += v;
                }
            }
        }
    }
}

// ---------------------------------------------------------------------------
// Attention: one block per (b,h). S=64, DH=64. qkv bf16 [N,1536]; o bf16 [N,512].
__global__ __launch_bounds__(256)
void attn_k(const bf16* __restrict__ qkv, bf16* __restrict__ o) {
    __shared__ bf16 qs[64 * 64], ks[64 * 64], vts[64 * 64], ps[64 * 64];
    const int tid = threadIdx.x;
    const int b = blockIdx.x >> 3;
    const int h = blockIdx.x & 7;
    const int lane = tid & 63;
    const int w = tid >> 6;

    // stage q,k row-major [t][d]; v transposed [d][t]
    #pragma unroll
    for (int half = 0; half < 2; half++) {
        int c = tid + half * 256;          // 512 chunks of 8 elems per matrix
        int trow = c >> 3;
        int off = (c & 7) * 8;
        const bf16* base = qkv + ((long)(trow * B_ + b)) * 1536 + h * 64 + off;
        *(uint4*)(qs + trow * 64 + off) = *(const uint4*)(base);
        *(uint4*)(ks + trow * 64 + off) = *(const uint4*)(base + 512);
        uint4 vv = *(const uint4*)(base + 1024);
        bf16 vtmp[8];
        *(uint4*)vtmp = vv;
        #pragma unroll
        for (int j = 0; j < 8; j++) vts[(off + j) * 64 + trow] = vtmp[j];
    }
    __syncthreads();

    const int lr = lane & 15, lq = lane >> 4;

    // scores strip: wave w owns query rows [w*16, w*16+16)
    f32x4 sc[4] = {};
    #pragma unroll
    for (int d0 = 0; d0 < 64; d0 += 32) {
        bf16x8 aq = *(const bf16x8*)(qs + (w * 16 + lr) * 64 + d0 + lq * 8);
        #pragma unroll
        for (int ni = 0; ni < 4; ni++) {
            bf16x8 bk = *(const bf16x8*)(ks + (ni * 16 + lr) * 64 + d0 + lq * 8);
            sc[ni] = __builtin_amdgcn_mfma_f32_16x16x32_bf16(aq, bk, sc[ni], 0, 0, 0);
        }
    }
    // softmax per row; row s = w*16 + lq*4 + r lives in the 16 lanes of quad lq
    float p[4][4];
    #pragma unroll
    for (int r = 0; r < 4; r++) {
        float m = -1e30f;
        #pragma unroll
        for (int ni = 0; ni < 4; ni++) { sc[ni][r] *= 0.125f; m = fmaxf(m, sc[ni][r]); }
        #pragma unroll
        for (int off = 1; off < 16; off <<= 1) m = fmaxf(m, __shfl_xor(m, off));
        float sum = 0.f;
        #pragma unroll
        for (int ni = 0; ni < 4; ni++) { p[ni][r] = __expf(sc[ni][r] - m); sum += p[ni][r]; }
        #pragma unroll
        for (int off = 1; off < 16; off <<= 1) sum += __shfl_xor(sum, off);
        float inv = 1.f / sum;
        #pragma unroll
        for (int ni = 0; ni < 4; ni++)
            ps[(w * 16 + lq * 4 + r) * 64 + ni * 16 + lr] = (bf16)(p[ni][r] * inv);
    }
    __syncthreads();  // P LDS round-trip (C/D layout -> A layout)

    // O strip = P[16x64] @ V[64x64]; vts is [d][t] so B-frag reads are contiguous
    f32x4 oa[4] = {};
    #pragma unroll
    for (int t0 = 0; t0 < 64; t0 += 32) {
        bf16x8 ap = *(const bf16x8*)(ps + (w * 16 + lr) * 64 + t0 + lq * 8);
        #pragma unroll
        for (int ni = 0; ni < 4; ni++) {
            bf16x8 bv = *(const bf16x8*)(vts + (ni * 16 + lr) * 64 + t0 + lq * 8);
            oa[ni] = __builtin_amdgcn_mfma_f32_16x16x32_bf16(ap, bv, oa[ni], 0, 0, 0);
        }
    }
    #pragma unroll
    for (int ni = 0; ni < 4; ni++) {
        #pragma unroll
        for (int r = 0; r < 4; r++) {
            int s = w * 16 + lq * 4 + r;
            int d = ni * 16 + lr;
            o[((long)(s * B_ + b)) * 512 + h * 64 + d] = (bf16)oa[ni][r];
        }
    }
}

// ---------------------------------------------------------------------------
// pooled = mean_s X; out = tanh(pooled @ hash_w^T + hash_b). fp32 throughout.
__global__ __launch_bounds__(256)
void poolhash_k(const float* __restrict__ X, const float* __restrict__ hw,
                const float* __restrict__ hb, float* __restrict__ out) {
    __shared__ float pooled[512];
    __shared__ float part[8][32];
    int b = blockIdx.x, tid = threadIdx.x;
    for (int d = tid; d < 512; d += 256) {
        float acc = 0.f;
        #pragma unroll 8
        for (int s = 0; s < 64; s++) acc += X[((long)(s * B_ + b)) * 512 + d];
        pooled[d] = acc * (1.f / 64.f);
    }
    __syncthreads();
    int k = tid & 31, ch = tid >> 5;
    float p = 0.f;
    for (int d = ch * 64; d < ch * 64 + 64; d++) p += pooled[d] * hw[k * 512 + d];
    part[ch][k] = p;
    __syncthreads();
    if (tid < 32) {
        float t = hb[tid];
        #pragma unroll
        for (int c = 0; c < 8; c++) t += part[c][tid];
        out[b * 32 + tid] = tanhf(t);
    }
}

// ---------------------------------------------------------------------------
extern "C" void kernel_launch(void* const* d_in, const int* in_sizes, int n_in,
                              void* d_out, int out_size, void* d_ws, size_t ws_size,
                              hipStream_t stream) {
    const float* x      = (const float*)d_in[0];
    const float* ln1_g  = (const float*)d_in[1];
    const float* ln1_b  = (const float*)d_in[2];
    const float* qkv_w  = (const float*)d_in[3];
    const float* qkv_b  = (const float*)d_in[4];
    const float* out_w  = (const float*)d_in[5];
    const float* out_b  = (const float*)d_in[6];
    const float* ln2_g  = (const float*)d_in[7];
    const float* ln2_b  = (const float*)d_in[8];
    const float* mlp_w1 = (const float*)d_in[9];
    const float* mlp_b1 = (const float*)d_in[10];
    const float* mlp_w2 = (const float*)d_in[11];
    const float* mlp_b2 = (const float*)d_in[12];
    const float* hash_w = (const float*)d_in[13];
    const float* hash_b = (const float*)d_in[14];

    // workspace layout (bytes)
    char* ws = (char*)d_ws;
    float* X  = (float*)ws;                                   // 134,217,728  fp32 residual
    bf16* BIG = (bf16*)(ws + 134217728);                      // 268,435,456  qkv[N,1536] / h1[N,2048] (time-aliased)
    bf16* Hb  = (bf16*)(ws + 134217728 + 268435456);          //  67,108,864  LN out / attn out [N,512]
    size_t wo = 134217728 + 268435456 + 67108864;
    bf16* Wq = (bf16*)(ws + wo);            wo += (size_t)NL_ * 1536 * 512 * 2;
    bf16* Wo = (bf16*)(ws + wo);            wo += (size_t)NL_ * 512 * 512 * 2;
    bf16* W1 = (bf16*)(ws + wo);            wo += (size_t)NL_ * 2048 * 512 * 2;
    bf16* W2 = (bf16*)(ws + wo);            wo += (size_t)NL_ * 512 * 2048 * 2;

    // convert weights to bf16 (every call; ws is re-poisoned)
    cvt_k<<<(NL_ * 1536 * 512) / 1024, 256, 0, stream>>>(qkv_w,  Wq, NL_ * 1536 * 512);
    cvt_k<<<(NL_ * 512  * 512) / 1024, 256, 0, stream>>>(out_w,  Wo, NL_ * 512  * 512);
    cvt_k<<<(NL_ * 2048 * 512) / 1024, 256, 0, stream>>>(mlp_w1, W1, NL_ * 2048 * 512);
    cvt_k<<<(NL_ * 512 * 2048) / 1024, 256, 0, stream>>>(mlp_w2, W2, NL_ * 512 * 2048);

    // X = x + PE
    pe_add_k<<<(NTOK * 256) / 256, 256, 0, stream>>>(x, X);

    for (int i = 0; i < NL_; i++) {
        // h = LN1(X) -> Hb (bf16)
        ln_k<<<NTOK / 4, 256, 0, stream>>>(X, ln1_g + i * 512, ln1_b + i * 512, Hb);
        // qkv = h @ Wq^T + b -> BIG (bf16 [N,1536])
        gemm_bt<0><<<dim3(12, 512), 256, 0, stream>>>(Hb, Wq + (size_t)i * 1536 * 512,
                                                      qkv_b + i * 1536, nullptr, BIG, 1536, 512);
        // attention -> Hb (bf16 [N,512])
        attn_k<<<B_ * H_, 256, 0, stream>>>(BIG, Hb);
        // X += o @ Wo^T + b
        gemm_bt<2><<<dim3(4, 512), 256, 0, stream>>>(Hb, Wo + (size_t)i * 512 * 512,
                                                     out_b + i * 512, X, nullptr, 512, 512);
        // h = LN2(X) -> Hb
        ln_k<<<NTOK / 4, 256, 0, stream>>>(X, ln2_g + i * 512, ln2_b + i * 512, Hb);
        // h1 = quickgelu(h @ W1^T + b1) -> BIG (bf16 [N,2048])
        gemm_bt<1><<<dim3(16, 512), 256, 0, stream>>>(Hb, W1 + (size_t)i * 2048 * 512,
                                                      mlp_b1 + i * 2048, nullptr, BIG, 2048, 512);
        // X += h1 @ W2^T + b2
        gemm_bt<2><<<dim3(4, 512), 256, 0, stream>>>(BIG, W2 + (size_t)i * 512 * 2048,
                                                     mlp_b2 + i * 512, X, nullptr, 512, 2048);
    }

    poolhash_k<<<B_, 256, 0, stream>>>(X, hash_w, hash_b, (float*)d_out);
}

// Round 2
// 3742.094 us; speedup vs baseline: 1.1697x; 1.1697x over previous
//
#include <hip/hip_runtime.h>
#include <hip/hip_bf16.h>
#include <math.h>

// Shapes (fixed by the reference)
#define S_   64
#define B_   1024
#define D_   512
#define H_   8
#define NL_  4
#define DH_  64
#define DFF_ 2048
#define NTOK (S_*B_)   // 65536 tokens

typedef __bf16 bf16;
typedef __bf16 bf16x8 __attribute__((ext_vector_type(8)));
typedef float  f32x4  __attribute__((ext_vector_type(4)));

#define AS1(p) ((__attribute__((address_space(1))) void*)(void*)(p))
#define AS3(p) ((__attribute__((address_space(3))) void*)(p))

// ---------------------------------------------------------------------------
// fp32 -> bf16 elementwise convert (weights; n multiple of 4)
__global__ __launch_bounds__(256) void cvt_k(const float* __restrict__ s,
                                             bf16* __restrict__ d, int n) {
    int i = (blockIdx.x * 256 + threadIdx.x) * 4;
    if (i < n) {
        float4 v = *(const float4*)(s + i);
        bf16 o4[4] = {(bf16)v.x, (bf16)v.y, (bf16)v.z, (bf16)v.w};
        *(ushort4*)(d + i) = *(const ushort4*)o4;  // 8B store
    }
}

// ---------------------------------------------------------------------------
// X = x + positional encoding (computed on the fly). One thread per (sin,cos) pair.
__global__ __launch_bounds__(256) void pe_add_k(const float* __restrict__ x,
                                                float* __restrict__ X) {
    int id = blockIdx.x * 256 + threadIdx.x;   // pair id
    int n = id >> 8;                            // token row = s*B+b
    int j = id & 255;                           // pair index, d = 2j
    int s = n >> 10;                            // n / B_
    float div = expf((float)j * -0.03597789207803197f);
    float ang = (float)s * div;
    const float inv = 0.04419417382415922f;     // 1/sqrt(512)
    float2 v = *(const float2*)(x + (long)n * 512 + 2 * j);
    v.x += sinf(ang) * inv;
    v.y += cosf(ang) * inv;
    *(float2*)(X + (long)n * 512 + 2 * j) = v;
}

// ---------------------------------------------------------------------------
// LayerNorm: one wave per row (D=512, 8 floats/lane), fp32 math, bf16 out.
__global__ __launch_bounds__(256) void ln_k(const float* __restrict__ X,
                                            const float* __restrict__ g,
                                            const float* __restrict__ be,
                                            bf16* __restrict__ out) {
    long row = (long)blockIdx.x * 4 + (threadIdx.x >> 6);
    int lane = threadIdx.x & 63;
    const float* xr = X + row * 512 + lane * 8;
    float4 v0 = *(const float4*)xr;
    float4 v1 = *(const float4*)(xr + 4);
    float vv[8] = {v0.x, v0.y, v0.z, v0.w, v1.x, v1.y, v1.z, v1.w};
    float s = 0.f, sq = 0.f;
    #pragma unroll
    for (int j = 0; j < 8; j++) { s += vv[j]; sq += vv[j] * vv[j]; }
    #pragma unroll
    for (int off = 1; off < 64; off <<= 1) {
        s  += __shfl_xor(s, off);
        sq += __shfl_xor(sq, off);
    }
    float mean = s * (1.f / 512.f);
    float var  = sq * (1.f / 512.f) - mean * mean;
    float rs = rsqrtf(var + 1e-5f);
    int d = lane * 8;
    bf16 o8[8];
    #pragma unroll
    for (int j = 0; j < 8; j++)
        o8[j] = (bf16)((vv[j] - mean) * rs * g[d + j] + be[d + j]);
    *(uint4*)(out + row * 512 + d) = *(const uint4*)o8;  // 16B store
}

// ---------------------------------------------------------------------------
// GEMM: C[n,m] = A[n,k] * Bw[m,k] + bias[m]  (B^T layout, both K-contiguous).
// 128x128 tile, BK=32, 4 waves, each wave 4x4 tiles of mfma_f32_16x16x32_bf16.
// EPI 0: write bf16. EPI 2: fp32 residual +=.
template<int EPI>
__global__ __launch_bounds__(256)
void gemm_bt(const bf16* __restrict__ A, const bf16* __restrict__ Bw,
             const float* __restrict__ bias, float* __restrict__ Xres,
             bf16* __restrict__ Obf, int Mdim, int K) {
    __shared__ bf16 As[128 * 32];
    __shared__ bf16 Bs[128 * 32];
    const int tid  = threadIdx.x;
    const int lane = tid & 63;
    const int wave = tid >> 6;
    const long rowBlk = (long)blockIdx.y * 128;
    const long colBlk = (long)blockIdx.x * 128;

    const int c0 = tid;
    const bf16* ag0 = A  + (rowBlk + (c0 >> 2)) * K + (c0 & 3) * 8;
    const bf16* ag1 = ag0 + 64 * (long)K;
    const bf16* bg0 = Bw + (colBlk + (c0 >> 2)) * K + (c0 & 3) * 8;
    const bf16* bg1 = bg0 + 64 * (long)K;
    bf16* al0 = As + c0 * 8;
    bf16* al1 = As + (c0 + 256) * 8;
    bf16* bl0 = Bs + c0 * 8;
    bf16* bl1 = Bs + (c0 + 256) * 8;

    const int wm = (wave >> 1) * 64, wn = (wave & 1) * 64;
    const int lr = lane & 15, lq = lane >> 4;

    f32x4 acc[4][4] = {};

    for (int k0 = 0; k0 < K; k0 += 32) {
        __builtin_amdgcn_global_load_lds(AS1(ag0 + k0), AS3(al0), 16, 0, 0);
        __builtin_amdgcn_global_load_lds(AS1(ag1 + k0), AS3(al1), 16, 0, 0);
        __builtin_amdgcn_global_load_lds(AS1(bg0 + k0), AS3(bl0), 16, 0, 0);
        __builtin_amdgcn_global_load_lds(AS1(bg1 + k0), AS3(bl1), 16, 0, 0);
        __syncthreads();
        bf16x8 af[4], bfr[4];
        #pragma unroll
        for (int mi = 0; mi < 4; mi++)
            af[mi] = *(const bf16x8*)(As + (wm + mi * 16 + lr) * 32 + lq * 8);
        #pragma unroll
        for (int ni = 0; ni < 4; ni++)
            bfr[ni] = *(const bf16x8*)(Bs + (wn + ni * 16 + lr) * 32 + lq * 8);
        #pragma unroll
        for (int mi = 0; mi < 4; mi++)
            #pragma unroll
            for (int ni = 0; ni < 4; ni++)
                acc[mi][ni] = __builtin_amdgcn_mfma_f32_16x16x32_bf16(
                    af[mi], bfr[ni], acc[mi][ni], 0, 0, 0);
        __syncthreads();
    }

    #pragma unroll
    for (int mi = 0; mi < 4; mi++) {
        #pragma unroll
        for (int ni = 0; ni < 4; ni++) {
            #pragma unroll
            for (int r = 0; r < 4; r++) {
                long row = rowBlk + wm + mi * 16 + lq * 4 + r;
                long col = colBlk + wn + ni * 16 + lr;
                float v = acc[mi][ni][r] + bias[col];
                if (EPI == 0) {
                    Obf[row * Mdim + col] = (bf16)v;
                } else {
                    Xres[row * Mdim + col] += v;
                }
            }
        }
    }
}

// ---------------------------------------------------------------------------
// Fused MLP: X += W2^T-proj( QuickGELU( LN2out @ W1^T + b1 ) ) + b2.
// Block = 64 rows, 4 waves. h1 never leaves the chip (LDS round-trip only).
// Stage-1 (per j-tile of 128 h1-cols): K=512 in 4 chunks of BK=128,
//   per wave 4x2 MFMA tiles, 32 MFMA per barrier-pair.
// Stage-2: 64x512 fp32 accumulator persistent in registers (128 VGPR/lane),
//   K-chunk = 128 per j in 4 sub-chunks of 32, per wave 4x8 tiles = 32 MFMA
//   per barrier-pair.
// All LDS frag reads <=2-way bank conflicts: staged buffers use a source-side
// XOR swizzle (global_load_lds dest must stay linear), h1s uses +8 padding.
__global__ __launch_bounds__(256, 2)
void fused_mlp(const bf16* __restrict__ A,   // [N,512] LN2 output
               const bf16* __restrict__ W1,  // [2048,512]
               const float* __restrict__ b1, // [2048]
               const bf16* __restrict__ W2,  // [512,2048]
               const float* __restrict__ b2, // [512]
               float* __restrict__ X) {      // [N,512] residual +=
    __shared__ bf16 As[64 * 128];    // 16 KB: A k-chunk [64 x 128]
    __shared__ bf16 Ws[16384];       // 32 KB: W1 tile [128x128] / W2 tile [512x32]
    __shared__ bf16 h1s[64 * 136];   // 17 KB: gelu'd h1 j-tile [64 x 128] (+8 pad)
    const int tid = threadIdx.x;
    const int lane = tid & 63;
    const int w = tid >> 6;
    const int lr = lane & 15, lq = lane >> 4;
    const long rowBlk = (long)blockIdx.x * 64;

    f32x4 acc2[4][8] = {};   // X rows 0..63 x cols [w*128, w*128+128)

    for (int j = 0; j < 16; j++) {
        f32x4 acc1[4][2] = {};   // h1 rows 0..63 x local cols [w*32, w*32+32)
        for (int kk = 0; kk < 4; kk++) {
            // stage A [64 x 128] — slot(row,ks) holds global ko = ks^(row&7)
            #pragma unroll
            for (int r = 0; r < 4; r++) {
                int c = tid + r * 256;
                int row = c >> 4, ks = c & 15;
                int ko = ks ^ (row & 7);
                __builtin_amdgcn_global_load_lds(
                    AS1(A + (rowBlk + row) * 512 + kk * 128 + ko * 8),
                    AS3(As + c * 8), 16, 0, 0);
            }
            // stage W1 tile [128 x 128], rows j*128..j*128+128
            #pragma unroll
            for (int r = 0; r < 8; r++) {
                int c = tid + r * 256;
                int n = c >> 4, ks = c & 15;
                int ko = ks ^ (n & 7);
                __builtin_amdgcn_global_load_lds(
                    AS1(W1 + ((long)j * 128 + n) * 512 + kk * 128 + ko * 8),
                    AS3(Ws + c * 8), 16, 0, 0);
            }
            __syncthreads();
            #pragma unroll
            for (int kh = 0; kh < 4; kh++) {
                bf16x8 af[4], bfx[2];
                #pragma unroll
                for (int ri = 0; ri < 4; ri++) {
                    int row = ri * 16 + lr;
                    int ks = (kh * 4 + lq) ^ (row & 7);
                    af[ri] = *(const bf16x8*)(As + row * 128 + ks * 8);
                }
                #pragma unroll
                for (int ci = 0; ci < 2; ci++) {
                    int n = w * 32 + ci * 16 + lr;
                    int ks = (kh * 4 + lq) ^ (n & 7);
                    bfx[ci] = *(const bf16x8*)(Ws + n * 128 + ks * 8);
                }
                #pragma unroll
                for (int ri = 0; ri < 4; ri++)
                    #pragma unroll
                    for (int ci = 0; ci < 2; ci++)
                        acc1[ri][ci] = __builtin_amdgcn_mfma_f32_16x16x32_bf16(
                            af[ri], bfx[ci], acc1[ri][ci], 0, 0, 0);
            }
            __syncthreads();
        }
        // bias + QuickGELU -> h1s (bf16), C/D layout: row=lq*4+r, col=lr
        #pragma unroll
        for (int ci = 0; ci < 2; ci++) {
            int col = w * 32 + ci * 16 + lr;
            float bv = b1[j * 128 + col];
            #pragma unroll
            for (int ri = 0; ri < 4; ri++) {
                #pragma unroll
                for (int r = 0; r < 4; r++) {
                    int row = ri * 16 + lq * 4 + r;
                    float v = acc1[ri][ci][r] + bv;
                    float g = v / (1.f + __expf(-1.702f * v));
                    h1s[row * 136 + col] = (bf16)g;
                }
            }
        }
        __syncthreads();
        // stage-2: acc2 += h1j[64x128] @ W2[:, j*128..+128]^T
        for (int kk2 = 0; kk2 < 4; kk2++) {
            // stage W2 tile [512 n x 32 k] — slot(n,ks): ko = ks^((n>>1)&3)
            #pragma unroll
            for (int r = 0; r < 8; r++) {
                int c = tid + r * 256;
                int n = c >> 2, ks = c & 3;
                int ko = ks ^ ((n >> 1) & 3);
                __builtin_amdgcn_global_load_lds(
                    AS1(W2 + (long)n * 2048 + j * 128 + kk2 * 32 + ko * 8),
                    AS3(Ws + c * 8), 16, 0, 0);
            }
            __syncthreads();
            bf16x8 af2[4], bf2[8];
            #pragma unroll
            for (int ri = 0; ri < 4; ri++)
                af2[ri] = *(const bf16x8*)(h1s + (ri * 16 + lr) * 136 + kk2 * 32 + lq * 8);
            #pragma unroll
            for (int ci = 0; ci < 8; ci++) {
                int n = w * 128 + ci * 16 + lr;
                int ks = lq ^ ((n >> 1) & 3);
                bf2[ci] = *(const bf16x8*)(Ws + n * 32 + ks * 8);
            }
            #pragma unroll
            for (int ri = 0; ri < 4; ri++)
                #pragma unroll
                for (int ci = 0; ci < 8; ci++)
                    acc2[ri][ci] = __builtin_amdgcn_mfma_f32_16x16x32_bf16(
                        af2[ri], bf2[ci], acc2[ri][ci], 0, 0, 0);
            __syncthreads();
        }
    }
    // epilogue: X += acc2 + b2
    #pragma unroll
    for (int ci = 0; ci < 8; ci++) {
        int col = w * 128 + ci * 16 + lr;
        float bv = b2[col];
        #pragma unroll
        for (int ri = 0; ri < 4; ri++) {
            #pragma unroll
            for (int r = 0; r < 4; r++) {
                long row = rowBlk + ri * 16 + lq * 4 + r;
                X[row * 512 + col] += acc2[ri][ci][r] + bv;
            }
        }
    }
}

// ---------------------------------------------------------------------------
// Attention: one block per (b,h). S=64, DH=64. qkv bf16 [N,1536]; o bf16 [N,512].
__global__ __launch_bounds__(256)
void attn_k(const bf16* __restrict__ qkv, bf16* __restrict__ o) {
    __shared__ bf16 qs[64 * 64], ks[64 * 64], vts[64 * 64], ps[64 * 64];
    const int tid = threadIdx.x;
    const int b = blockIdx.x >> 3;
    const int h = blockIdx.x & 7;
    const int lane = tid & 63;
    const int w = tid >> 6;

    #pragma unroll
    for (int half = 0; half < 2; half++) {
        int c = tid + half * 256;
        int trow = c >> 3;
        int off = (c & 7) * 8;
        const bf16* base = qkv + ((long)(trow * B_ + b)) * 1536 + h * 64 + off;
        *(uint4*)(qs + trow * 64 + off) = *(const uint4*)(base);
        *(uint4*)(ks + trow * 64 + off) = *(const uint4*)(base + 512);
        uint4 vv = *(const uint4*)(base + 1024);
        bf16 vtmp[8];
        *(uint4*)vtmp = vv;
        #pragma unroll
        for (int j = 0; j < 8; j++) vts[(off + j) * 64 + trow] = vtmp[j];
    }
    __syncthreads();

    const int lr = lane & 15, lq = lane >> 4;

    f32x4 sc[4] = {};
    #pragma unroll
    for (int d0 = 0; d0 < 64; d0 += 32) {
        bf16x8 aq = *(const bf16x8*)(qs + (w * 16 + lr) * 64 + d0 + lq * 8);
        #pragma unroll
        for (int ni = 0; ni < 4; ni++) {
            bf16x8 bk = *(const bf16x8*)(ks + (ni * 16 + lr) * 64 + d0 + lq * 8);
            sc[ni] = __builtin_amdgcn_mfma_f32_16x16x32_bf16(aq, bk, sc[ni], 0, 0, 0);
        }
    }
    float p[4][4];
    #pragma unroll
    for (int r = 0; r < 4; r++) {
        float m = -1e30f;
        #pragma unroll
        for (int ni = 0; ni < 4; ni++) { sc[ni][r] *= 0.125f; m = fmaxf(m, sc[ni][r]); }
        #pragma unroll
        for (int off = 1; off < 16; off <<= 1) m = fmaxf(m, __shfl_xor(m, off));
        float sum = 0.f;
        #pragma unroll
        for (int ni = 0; ni < 4; ni++) { p[ni][r] = __expf(sc[ni][r] - m); sum += p[ni][r]; }
        #pragma unroll
        for (int off = 1; off < 16; off <<= 1) sum += __shfl_xor(sum, off);
        float inv = 1.f / sum;
        #pragma unroll
        for (int ni = 0; ni < 4; ni++)
            ps[(w * 16 + lq * 4 + r) * 64 + ni * 16 + lr] = (bf16)(p[ni][r] * inv);
    }
    __syncthreads();

    f32x4 oa[4] = {};
    #pragma unroll
    for (int t0 = 0; t0 < 64; t0 += 32) {
        bf16x8 ap = *(const bf16x8*)(ps + (w * 16 + lr) * 64 + t0 + lq * 8);
        #pragma unroll
        for (int ni = 0; ni < 4; ni++) {
            bf16x8 bv = *(const bf16x8*)(vts + (ni * 16 + lr) * 64 + t0 + lq * 8);
            oa[ni] = __builtin_amdgcn_mfma_f32_16x16x32_bf16(ap, bv, oa[ni], 0, 0, 0);
        }
    }
    #pragma unroll
    for (int ni = 0; ni < 4; ni++) {
        #pragma unroll
        for (int r = 0; r < 4; r++) {
            int s = w * 16 + lq * 4 + r;
            int d = ni * 16 + lr;
            o[((long)(s * B_ + b)) * 512 + h * 64 + d] = (bf16)oa[ni][r];
        }
    }
}

// ---------------------------------------------------------------------------
// pooled = mean_s X; out = tanh(pooled @ hash_w^T + hash_b). fp32 throughout.
__global__ __launch_bounds__(256)
void poolhash_k(const float* __restrict__ X, const float* __restrict__ hw,
                const float* __restrict__ hb, float* __restrict__ out) {
    __shared__ float pooled[512];
    __shared__ float part[8][32];
    int b = blockIdx.x, tid = threadIdx.x;
    for (int d = tid; d < 512; d += 256) {
        float acc = 0.f;
        #pragma unroll 8
        for (int s = 0; s < 64; s++) acc += X[((long)(s * B_ + b)) * 512 + d];
        pooled[d] = acc * (1.f / 64.f);
    }
    __syncthreads();
    int k = tid & 31, ch = tid >> 5;
    float p = 0.f;
    for (int d = ch * 64; d < ch * 64 + 64; d++) p += pooled[d] * hw[k * 512 + d];
    part[ch][k] = p;
    __syncthreads();
    if (tid < 32) {
        float t = hb[tid];
        #pragma unroll
        for (int c = 0; c < 8; c++) t += part[c][tid];
        out[b * 32 + tid] = tanhf(t);
    }
}

// ---------------------------------------------------------------------------
extern "C" void kernel_launch(void* const* d_in, const int* in_sizes, int n_in,
                              void* d_out, int out_size, void* d_ws, size_t ws_size,
                              hipStream_t stream) {
    const float* x      = (const float*)d_in[0];
    const float* ln1_g  = (const float*)d_in[1];
    const float* ln1_b  = (const float*)d_in[2];
    const float* qkv_w  = (const float*)d_in[3];
    const float* qkv_b  = (const float*)d_in[4];
    const float* out_w  = (const float*)d_in[5];
    const float* out_b  = (const float*)d_in[6];
    const float* ln2_g  = (const float*)d_in[7];
    const float* ln2_b  = (const float*)d_in[8];
    const float* mlp_w1 = (const float*)d_in[9];
    const float* mlp_b1 = (const float*)d_in[10];
    const float* mlp_w2 = (const float*)d_in[11];
    const float* mlp_b2 = (const float*)d_in[12];
    const float* hash_w = (const float*)d_in[13];
    const float* hash_b = (const float*)d_in[14];

    // workspace layout (bytes)
    char* ws = (char*)d_ws;
    float* X  = (float*)ws;                                   // 134,217,728  fp32 residual
    bf16* BIG = (bf16*)(ws + 134217728);                      // qkv [N,1536] bf16
    bf16* Hb  = (bf16*)(ws + 134217728 + 268435456);          // LN out / attn out [N,512]
    size_t wo = 134217728 + 268435456 + 67108864;
    bf16* Wq = (bf16*)(ws + wo);            wo += (size_t)NL_ * 1536 * 512 * 2;
    bf16* Wo = (bf16*)(ws + wo);            wo += (size_t)NL_ * 512 * 512 * 2;
    bf16* W1 = (bf16*)(ws + wo);            wo += (size_t)NL_ * 2048 * 512 * 2;
    bf16* W2 = (bf16*)(ws + wo);            wo += (size_t)NL_ * 512 * 2048 * 2;

    // convert weights to bf16 (every call; ws is re-poisoned)
    cvt_k<<<(NL_ * 1536 * 512) / 1024, 256, 0, stream>>>(qkv_w,  Wq, NL_ * 1536 * 512);
    cvt_k<<<(NL_ * 512  * 512) / 1024, 256, 0, stream>>>(out_w,  Wo, NL_ * 512  * 512);
    cvt_k<<<(NL_ * 2048 * 512) / 1024, 256, 0, stream>>>(mlp_w1, W1, NL_ * 2048 * 512);
    cvt_k<<<(NL_ * 512 * 2048) / 1024, 256, 0, stream>>>(mlp_w2, W2, NL_ * 512 * 2048);

    // X = x + PE
    pe_add_k<<<(NTOK * 256) / 256, 256, 0, stream>>>(x, X);

    for (int i = 0; i < NL_; i++) {
        // h = LN1(X) -> Hb (bf16)
        ln_k<<<NTOK / 4, 256, 0, stream>>>(X, ln1_g + i * 512, ln1_b + i * 512, Hb);
        // qkv = h @ Wq^T + b -> BIG (bf16 [N,1536])
        gemm_bt<0><<<dim3(12, 512), 256, 0, stream>>>(Hb, Wq + (size_t)i * 1536 * 512,
                                                      qkv_b + i * 1536, nullptr, BIG, 1536, 512);
        // attention -> Hb (bf16 [N,512])
        attn_k<<<B_ * H_, 256, 0, stream>>>(BIG, Hb);
        // X += o @ Wo^T + b
        gemm_bt<2><<<dim3(4, 512), 256, 0, stream>>>(Hb, Wo + (size_t)i * 512 * 512,
                                                     out_b + i * 512, X, nullptr, 512, 512);
        // h = LN2(X) -> Hb
        ln_k<<<NTOK / 4, 256, 0, stream>>>(X, ln2_g + i * 512, ln2_b + i * 512, Hb);
        // X += W2-proj(quickgelu(h @ W1^T + b1)) + b2   (fused, h1 stays on-chip)
        fused_mlp<<<NTOK / 64, 256, 0, stream>>>(Hb, W1 + (size_t)i * 2048 * 512,
                                                 mlp_b1 + i * 2048,
                                                 W2 + (size_t)i * 512 * 2048,
                                                 mlp_b2 + i * 512, X);
    }

    poolhash_k<<<B_, 256, 0, stream>>>(X, hash_w, hash_b, (float*)d_out);
}